// Round 1
// baseline (234.204 us; speedup 1.0000x reference)
//
#include <hip/hip_runtime.h>
#include <hip/hip_bf16.h>

typedef __attribute__((ext_vector_type(8))) short short8;
typedef __attribute__((ext_vector_type(4))) short short4v;
typedef __attribute__((ext_vector_type(4))) float f32x4;

#define TT 4096
#define DM 1024
#define NH 16
#define NPROJ 1280   // 128 qs + 128 ks + 256 qg + 256 kg + 512 v
#define DATTN 512

static __device__ __forceinline__ short f2bf(float f) {
  __hip_bfloat16 h = __float2bfloat16(f);
  return *reinterpret_cast<short*>(&h);
}
static __device__ __forceinline__ float bf2f(__hip_bfloat16 h) { return __bfloat162float(h); }

// ---------------- fp32 -> bf16 convert (x, out_w) ----------------
__global__ __launch_bounds__(256) void k_f32_to_bf16(const float* __restrict__ in,
                                                     __hip_bfloat16* __restrict__ out, int n4) {
  int i = blockIdx.x * blockDim.x + threadIdx.x;
  if (i >= n4) return;
  float4 v = reinterpret_cast<const float4*>(in)[i];
  short4v o;
  o[0] = f2bf(v.x); o[1] = f2bf(v.y); o[2] = f2bf(v.z); o[3] = f2bf(v.w);
  reinterpret_cast<short4v*>(out)[i] = o;
}

// ---------------- concat 5 weight matrices into (1280,1024) bf16 ----------------
__global__ __launch_bounds__(256) void k_pack_wcat(const float* __restrict__ qs,
    const float* __restrict__ ks, const float* __restrict__ qg, const float* __restrict__ kg,
    const float* __restrict__ vw, __hip_bfloat16* __restrict__ w, int n4) {
  int i = blockIdx.x * blockDim.x + threadIdx.x;
  if (i >= n4) return;
  int idx = i * 4;
  int row = idx >> 10;
  int col = idx & 1023;
  const float* src;
  if (row < 128)      src = qs + (size_t)row * DM;
  else if (row < 256) src = ks + (size_t)(row - 128) * DM;
  else if (row < 512) src = qg + (size_t)(row - 256) * DM;
  else if (row < 768) src = kg + (size_t)(row - 512) * DM;
  else                src = vw + (size_t)(row - 768) * DM;
  float4 v = *reinterpret_cast<const float4*>(src + col);
  short4v o;
  o[0] = f2bf(v.x); o[1] = f2bf(v.y); o[2] = f2bf(v.z); o[3] = f2bf(v.w);
  *reinterpret_cast<short4v*>(w + idx) = o;
}

// ---------------- bf16 GEMM, B^T layout: C[m][n] = sum_k A[m][k]*B[n][k] ----------------
// BM=BN=128, BK=32, 256 threads = 4 waves (2x2), 64x64 per wave, 16x16x32 MFMA.
template<int OUT_BF16>
__global__ __launch_bounds__(256) void k_gemm_bt(const __hip_bfloat16* __restrict__ A,
    const __hip_bfloat16* __restrict__ B, void* __restrict__ Cv, int M, int N, int K) {
  __shared__ alignas(16) __hip_bfloat16 lA[128 * 32];
  __shared__ alignas(16) __hip_bfloat16 lB[128 * 32];
  const int tid = threadIdx.x;
  const int lane = tid & 63;
  const int wid = tid >> 6;
  const int m0 = blockIdx.x * 128, n0 = blockIdx.y * 128;
  const int wm = (wid >> 1) * 64, wn = (wid & 1) * 64;
  const int srow = tid >> 2;          // 0..63
  const int scol = (tid & 3) * 8;     // bf16 elements
  const int fr = lane & 15, fk = (lane >> 4) * 8;
  f32x4 acc[4][4];
  const f32x4 zz = {0.f, 0.f, 0.f, 0.f};
#pragma unroll
  for (int m = 0; m < 4; ++m)
#pragma unroll
    for (int n = 0; n < 4; ++n) acc[m][n] = zz;

  for (int kt = 0; kt < K; kt += 32) {
    __syncthreads();
    {
      const __hip_bfloat16* ga0 = A + (size_t)(m0 + srow) * K + kt + scol;
      const __hip_bfloat16* ga1 = A + (size_t)(m0 + 64 + srow) * K + kt + scol;
      const __hip_bfloat16* gb0 = B + (size_t)(n0 + srow) * K + kt + scol;
      const __hip_bfloat16* gb1 = B + (size_t)(n0 + 64 + srow) * K + kt + scol;
      __builtin_amdgcn_global_load_lds((const __attribute__((address_space(1))) void*)ga0,
          (__attribute__((address_space(3))) void*)(lA + srow * 32 + scol), 16, 0, 0);
      __builtin_amdgcn_global_load_lds((const __attribute__((address_space(1))) void*)ga1,
          (__attribute__((address_space(3))) void*)(lA + (64 + srow) * 32 + scol), 16, 0, 0);
      __builtin_amdgcn_global_load_lds((const __attribute__((address_space(1))) void*)gb0,
          (__attribute__((address_space(3))) void*)(lB + srow * 32 + scol), 16, 0, 0);
      __builtin_amdgcn_global_load_lds((const __attribute__((address_space(1))) void*)gb1,
          (__attribute__((address_space(3))) void*)(lB + (64 + srow) * 32 + scol), 16, 0, 0);
    }
    __syncthreads();
    short8 af[4], bfr[4];
#pragma unroll
    for (int m = 0; m < 4; ++m)
      af[m] = *reinterpret_cast<const short8*>(lA + (wm + m * 16 + fr) * 32 + fk);
#pragma unroll
    for (int n = 0; n < 4; ++n)
      bfr[n] = *reinterpret_cast<const short8*>(lB + (wn + n * 16 + fr) * 32 + fk);
#pragma unroll
    for (int m = 0; m < 4; ++m)
#pragma unroll
      for (int n = 0; n < 4; ++n)
        acc[m][n] = __builtin_amdgcn_mfma_f32_16x16x32_bf16(af[m], bfr[n], acc[m][n], 0, 0, 0);
  }
  const int cr = (lane >> 4) * 4, cc = lane & 15;
#pragma unroll
  for (int m = 0; m < 4; ++m)
#pragma unroll
    for (int n = 0; n < 4; ++n)
#pragma unroll
      for (int j = 0; j < 4; ++j) {
        const int row = m0 + wm + m * 16 + cr + j;
        const int col = n0 + wn + n * 16 + cc;
        if (OUT_BF16)
          ((__hip_bfloat16*)Cv)[(size_t)row * N + col] = __float2bfloat16(acc[m][n][j]);
        else
          ((float*)Cv)[(size_t)row * N + col] = acc[m][n][j];
      }
}

// ---------------- RoPE + pack Q/K (H,T,32) and V^T (H,32,T), fold scale*exp(ls) into Q ----
__global__ __launch_bounds__(256) void k_rope_pack(const __hip_bfloat16* __restrict__ proj,
    const float* __restrict__ ls, const int* __restrict__ posp,
    __hip_bfloat16* __restrict__ Qp, __hip_bfloat16* __restrict__ Kp,
    __hip_bfloat16* __restrict__ Vt) {
  const int gid = blockIdx.x * blockDim.x + threadIdx.x;  // T*NH, t fastest
  const int t = gid & (TT - 1);
  const int h = gid >> 12;
  const __hip_bfloat16* pr = proj + (size_t)t * NPROJ;
  const float qscale = 0.20412414523193154f * __expf(ls[h]);  // 1/sqrt(24) * exp(logit_scale)
  const float pos = (float)(t + posp[0]);
  // inv_freq[i] = 10000^(-i/8) = 10^(-i/2)
  const float invf[8] = {1.0f, 0.31622776601683794f, 0.1f, 0.031622776601683794f,
                         0.01f, 0.0031622776601683794f, 0.001f, 0.00031622776601683794f};
  short8 qv[4], kv[4];
  const short8 z8 = {0, 0, 0, 0, 0, 0, 0, 0};
  qv[3] = z8; kv[3] = z8;
#pragma unroll
  for (int i = 0; i < 8; ++i) {
    qv[0][i] = f2bf(bf2f(pr[h * 8 + i]) * qscale);
    kv[0][i] = f2bf(bf2f(pr[128 + h * 8 + i]));
  }
#pragma unroll
  for (int i = 0; i < 8; ++i) {
    const float ang = pos * invf[i];
    float ss, cc;
    __sincosf(ang, &ss, &cc);
    const float x1q = bf2f(pr[256 + h * 16 + i]), x2q = bf2f(pr[256 + h * 16 + 8 + i]);
    const float x1k = bf2f(pr[512 + h * 16 + i]), x2k = bf2f(pr[512 + h * 16 + 8 + i]);
    qv[1][i] = f2bf((x1q * cc - x2q * ss) * qscale);
    qv[2][i] = f2bf((x1q * ss + x2q * cc) * qscale);
    kv[1][i] = f2bf(x1k * cc - x2k * ss);
    kv[2][i] = f2bf(x1k * ss + x2k * cc);
  }
  short8* qdst = reinterpret_cast<short8*>(Qp + ((size_t)h * TT + t) * 32);
  short8* kdst = reinterpret_cast<short8*>(Kp + ((size_t)h * TT + t) * 32);
#pragma unroll
  for (int p = 0; p < 4; ++p) { qdst[p] = qv[p]; kdst[p] = kv[p]; }
#pragma unroll
  for (int i = 0; i < 32; ++i)
    Vt[((size_t)h * 32 + i) * TT + t] = pr[768 + h * 32 + i];
}

// ---------------- causal flash attention, 16x16x32 MFMA ----------------
// grid (T/64, H), 256 threads = 4 waves, each wave 16 q-rows, KV tiles of 64.
__global__ __launch_bounds__(256) void k_attn(const __hip_bfloat16* __restrict__ Qp,
    const __hip_bfloat16* __restrict__ Kp, const __hip_bfloat16* __restrict__ Vt,
    __hip_bfloat16* __restrict__ Ob) {
  __shared__ alignas(16) __hip_bfloat16 Plds[4][16][72];
  const int h = blockIdx.y;
  const int tid = threadIdx.x;
  const int lane = tid & 63, w = tid >> 6;
  const int q0 = blockIdx.x * 64 + w * 16;
  const int g = lane >> 4, c = lane & 15;
  const short8 qf = *reinterpret_cast<const short8*>(Qp + ((size_t)h * TT + q0 + c) * 32 + 8 * g);
  f32x4 o0 = {0.f, 0.f, 0.f, 0.f}, o1 = {0.f, 0.f, 0.f, 0.f};
  const f32x4 zz = {0.f, 0.f, 0.f, 0.f};
  float mst[4] = {-1e30f, -1e30f, -1e30f, -1e30f};
  float lsum[4] = {0.f, 0.f, 0.f, 0.f};
  const int ntiles = blockIdx.x + 1;
  for (int it = 0; it < ntiles; ++it) {
    const int kv0 = it * 64;
    f32x4 s[4];
#pragma unroll
    for (int ct = 0; ct < 4; ++ct) {
      const short8 kf =
          *reinterpret_cast<const short8*>(Kp + ((size_t)h * TT + kv0 + ct * 16 + c) * 32 + 8 * g);
      s[ct] = __builtin_amdgcn_mfma_f32_16x16x32_bf16(qf, kf, zz, 0, 0, 0);
    }
    if (kv0 + 63 > q0) {  // diagonal tile for this wave: apply causal mask
#pragma unroll
      for (int ct = 0; ct < 4; ++ct)
#pragma unroll
        for (int j = 0; j < 4; ++j)
          if (kv0 + ct * 16 + c > q0 + g * 4 + j) s[ct][j] = -1e30f;
    }
#pragma unroll
    for (int j = 0; j < 4; ++j) {
      float mx = fmaxf(fmaxf(s[0][j], s[1][j]), fmaxf(s[2][j], s[3][j]));
      mx = fmaxf(mx, __shfl_xor(mx, 1, 64));
      mx = fmaxf(mx, __shfl_xor(mx, 2, 64));
      mx = fmaxf(mx, __shfl_xor(mx, 4, 64));
      mx = fmaxf(mx, __shfl_xor(mx, 8, 64));
      const float nm = fmaxf(mst[j], mx);
      float sum = 0.f;
#pragma unroll
      for (int ct = 0; ct < 4; ++ct) {
        const float p = __expf(s[ct][j] - nm);
        s[ct][j] = p;
        sum += p;
      }
      sum += __shfl_xor(sum, 1, 64);
      sum += __shfl_xor(sum, 2, 64);
      sum += __shfl_xor(sum, 4, 64);
      sum += __shfl_xor(sum, 8, 64);
      const float alpha = __expf(mst[j] - nm);
      lsum[j] = lsum[j] * alpha + sum;
      mst[j] = nm;
      o0[j] *= alpha;
      o1[j] *= alpha;
    }
    __syncthreads();  // protect Plds WAR (previous iter reads done)
#pragma unroll
    for (int ct = 0; ct < 4; ++ct)
#pragma unroll
      for (int j = 0; j < 4; ++j)
        Plds[w][g * 4 + j][ct * 16 + c] = __float2bfloat16(s[ct][j]);
    __syncthreads();  // publish P
    const short8 pf0 = *reinterpret_cast<const short8*>(&Plds[w][c][8 * g]);
    const short8 pf1 = *reinterpret_cast<const short8*>(&Plds[w][c][32 + 8 * g]);
    const size_t vbase = ((size_t)h * 32 + c) * TT + kv0 + 8 * g;
    const short8 v00 = *reinterpret_cast<const short8*>(Vt + vbase);
    const short8 v01 = *reinterpret_cast<const short8*>(Vt + vbase + 32);
    const short8 v10 = *reinterpret_cast<const short8*>(Vt + vbase + (size_t)16 * TT);
    const short8 v11 = *reinterpret_cast<const short8*>(Vt + vbase + (size_t)16 * TT + 32);
    o0 = __builtin_amdgcn_mfma_f32_16x16x32_bf16(pf0, v00, o0, 0, 0, 0);
    o0 = __builtin_amdgcn_mfma_f32_16x16x32_bf16(pf1, v01, o0, 0, 0, 0);
    o1 = __builtin_amdgcn_mfma_f32_16x16x32_bf16(pf0, v10, o1, 0, 0, 0);
    o1 = __builtin_amdgcn_mfma_f32_16x16x32_bf16(pf1, v11, o1, 0, 0, 0);
  }
#pragma unroll
  for (int j = 0; j < 4; ++j) {
    const float inv = 1.0f / lsum[j];
    const int row = q0 + g * 4 + j;
    Ob[(size_t)row * DATTN + h * 32 + c] = __float2bfloat16(o0[j] * inv);
    Ob[(size_t)row * DATTN + h * 32 + 16 + c] = __float2bfloat16(o1[j] * inv);
  }
}

extern "C" void kernel_launch(void* const* d_in, const int* in_sizes, int n_in,
                              void* d_out, int out_size, void* d_ws, size_t ws_size,
                              hipStream_t stream) {
  const float* x   = (const float*)d_in[0];
  const float* qsw = (const float*)d_in[1];
  const float* ksw = (const float*)d_in[2];
  const float* qgw = (const float*)d_in[3];
  const float* kgw = (const float*)d_in[4];
  const float* vw  = (const float*)d_in[5];
  const float* ow  = (const float*)d_in[6];
  const float* ls  = (const float*)d_in[7];
  const int* posp  = (const int*)d_in[9];
  float* out = (float*)d_out;

  size_t off = 0;
  auto alloc = [&](size_t bytes) {
    char* p = (char*)d_ws + off;
    off += (bytes + 255) & ~(size_t)255;
    return (void*)p;
  };
  __hip_bfloat16* Xbf  = (__hip_bfloat16*)alloc((size_t)TT * DM * 2);
  __hip_bfloat16* Wcat = (__hip_bfloat16*)alloc((size_t)NPROJ * DM * 2);
  __hip_bfloat16* OW   = (__hip_bfloat16*)alloc((size_t)DM * DATTN * 2);
  __hip_bfloat16* proj = (__hip_bfloat16*)alloc((size_t)TT * NPROJ * 2);
  __hip_bfloat16* Qp   = (__hip_bfloat16*)alloc((size_t)NH * TT * 32 * 2);
  __hip_bfloat16* Kpk  = (__hip_bfloat16*)alloc((size_t)NH * TT * 32 * 2);
  __hip_bfloat16* Vt   = (__hip_bfloat16*)alloc((size_t)NH * 32 * TT * 2);
  __hip_bfloat16* Ob   = (__hip_bfloat16*)alloc((size_t)TT * DATTN * 2);

  k_f32_to_bf16<<<dim3((TT * DM / 4) / 256), 256, 0, stream>>>(x, Xbf, TT * DM / 4);
  k_f32_to_bf16<<<dim3((DM * DATTN / 4) / 256), 256, 0, stream>>>(ow, OW, DM * DATTN / 4);
  k_pack_wcat<<<dim3((NPROJ * DM / 4) / 256), 256, 0, stream>>>(qsw, ksw, qgw, kgw, vw, Wcat,
                                                                NPROJ * DM / 4);
  k_gemm_bt<1><<<dim3(TT / 128, NPROJ / 128), 256, 0, stream>>>(Xbf, Wcat, (void*)proj,
                                                                TT, NPROJ, DM);
  k_rope_pack<<<dim3(TT * NH / 256), 256, 0, stream>>>(proj, ls, posp, Qp, Kpk, Vt);
  k_attn<<<dim3(TT / 64, NH), 256, 0, stream>>>(Qp, Kpk, Vt, Ob);
  k_gemm_bt<0><<<dim3(TT / 128, DM / 128), 256, 0, stream>>>(Ob, OW, (void*)d_out,
                                                             TT, DM, DATTN);
}

// Round 2
// 212.863 us; speedup vs baseline: 1.1003x; 1.1003x over previous
//
#include <hip/hip_runtime.h>
#include <hip/hip_bf16.h>

typedef __attribute__((ext_vector_type(8))) short short8;
typedef __attribute__((ext_vector_type(4))) short short4v;
typedef __attribute__((ext_vector_type(4))) float f32x4;

#define TT 4096
#define DM 1024
#define NH 16
#define NPROJ 1280   // 128 qs + 128 ks + 256 qg + 256 kg + 512 v
#define DATTN 512

static __device__ __forceinline__ short f2bf(float f) {
  __hip_bfloat16 h = __float2bfloat16(f);
  return *reinterpret_cast<short*>(&h);
}
static __device__ __forceinline__ float bf2f(__hip_bfloat16 h) { return __bfloat162float(h); }

// ---------------- fp32 -> bf16 convert (x, out_w) ----------------
__global__ __launch_bounds__(256) void k_f32_to_bf16(const float* __restrict__ in,
                                                     __hip_bfloat16* __restrict__ out, int n4) {
  int i = blockIdx.x * blockDim.x + threadIdx.x;
  if (i >= n4) return;
  float4 v = reinterpret_cast<const float4*>(in)[i];
  short4v o;
  o[0] = f2bf(v.x); o[1] = f2bf(v.y); o[2] = f2bf(v.z); o[3] = f2bf(v.w);
  reinterpret_cast<short4v*>(out)[i] = o;
}

// ---------------- concat 5 weight matrices into (1280,1024) bf16 ----------------
__global__ __launch_bounds__(256) void k_pack_wcat(const float* __restrict__ qs,
    const float* __restrict__ ks, const float* __restrict__ qg, const float* __restrict__ kg,
    const float* __restrict__ vw, __hip_bfloat16* __restrict__ w, int n4) {
  int i = blockIdx.x * blockDim.x + threadIdx.x;
  if (i >= n4) return;
  int idx = i * 4;
  int row = idx >> 10;
  int col = idx & 1023;
  const float* src;
  if (row < 128)      src = qs + (size_t)row * DM;
  else if (row < 256) src = ks + (size_t)(row - 128) * DM;
  else if (row < 512) src = qg + (size_t)(row - 256) * DM;
  else if (row < 768) src = kg + (size_t)(row - 512) * DM;
  else                src = vw + (size_t)(row - 768) * DM;
  float4 v = *reinterpret_cast<const float4*>(src + col);
  short4v o;
  o[0] = f2bf(v.x); o[1] = f2bf(v.y); o[2] = f2bf(v.z); o[3] = f2bf(v.w);
  *reinterpret_cast<short4v*>(w + idx) = o;
}

// ---------------- bf16 GEMM, B^T layout: C[m][n] = sum_k A[m][k]*B[n][k] ----------------
template<int OUT_BF16>
__global__ __launch_bounds__(256) void k_gemm_bt(const __hip_bfloat16* __restrict__ A,
    const __hip_bfloat16* __restrict__ B, void* __restrict__ Cv, int M, int N, int K) {
  __shared__ alignas(16) __hip_bfloat16 lA[128 * 32];
  __shared__ alignas(16) __hip_bfloat16 lB[128 * 32];
  const int tid = threadIdx.x;
  const int lane = tid & 63;
  const int wid = tid >> 6;
  const int m0 = blockIdx.x * 128, n0 = blockIdx.y * 128;
  const int wm = (wid >> 1) * 64, wn = (wid & 1) * 64;
  const int srow = tid >> 2;          // 0..63
  const int scol = (tid & 3) * 8;     // bf16 elements
  const int fr = lane & 15, fk = (lane >> 4) * 8;
  f32x4 acc[4][4];
  const f32x4 zz = {0.f, 0.f, 0.f, 0.f};
#pragma unroll
  for (int m = 0; m < 4; ++m)
#pragma unroll
    for (int n = 0; n < 4; ++n) acc[m][n] = zz;

  for (int kt = 0; kt < K; kt += 32) {
    __syncthreads();
    {
      const __hip_bfloat16* ga0 = A + (size_t)(m0 + srow) * K + kt + scol;
      const __hip_bfloat16* ga1 = A + (size_t)(m0 + 64 + srow) * K + kt + scol;
      const __hip_bfloat16* gb0 = B + (size_t)(n0 + srow) * K + kt + scol;
      const __hip_bfloat16* gb1 = B + (size_t)(n0 + 64 + srow) * K + kt + scol;
      __builtin_amdgcn_global_load_lds((const __attribute__((address_space(1))) void*)ga0,
          (__attribute__((address_space(3))) void*)(lA + srow * 32 + scol), 16, 0, 0);
      __builtin_amdgcn_global_load_lds((const __attribute__((address_space(1))) void*)ga1,
          (__attribute__((address_space(3))) void*)(lA + (64 + srow) * 32 + scol), 16, 0, 0);
      __builtin_amdgcn_global_load_lds((const __attribute__((address_space(1))) void*)gb0,
          (__attribute__((address_space(3))) void*)(lB + srow * 32 + scol), 16, 0, 0);
      __builtin_amdgcn_global_load_lds((const __attribute__((address_space(1))) void*)gb1,
          (__attribute__((address_space(3))) void*)(lB + (64 + srow) * 32 + scol), 16, 0, 0);
    }
    __syncthreads();
    short8 af[4], bfr[4];
#pragma unroll
    for (int m = 0; m < 4; ++m)
      af[m] = *reinterpret_cast<const short8*>(lA + (wm + m * 16 + fr) * 32 + fk);
#pragma unroll
    for (int n = 0; n < 4; ++n)
      bfr[n] = *reinterpret_cast<const short8*>(lB + (wn + n * 16 + fr) * 32 + fk);
#pragma unroll
    for (int m = 0; m < 4; ++m)
#pragma unroll
      for (int n = 0; n < 4; ++n)
        acc[m][n] = __builtin_amdgcn_mfma_f32_16x16x32_bf16(af[m], bfr[n], acc[m][n], 0, 0, 0);
  }
  const int cr = (lane >> 4) * 4, cc = lane & 15;
#pragma unroll
  for (int m = 0; m < 4; ++m)
#pragma unroll
    for (int n = 0; n < 4; ++n)
#pragma unroll
      for (int j = 0; j < 4; ++j) {
        const int row = m0 + wm + m * 16 + cr + j;
        const int col = n0 + wn + n * 16 + cc;
        if (OUT_BF16)
          ((__hip_bfloat16*)Cv)[(size_t)row * N + col] = __float2bfloat16(acc[m][n][j]);
        else
          ((float*)Cv)[(size_t)row * N + col] = acc[m][n][j];
      }
}

// ---------------- RoPE + pack Q/K (H,T,32) and V^T (H,32,T) ----------------
// qscale folds 1/sqrt(24) * exp(logit_scale) * log2(e)  (softmax uses exp2)
__global__ __launch_bounds__(256) void k_rope_pack(const __hip_bfloat16* __restrict__ proj,
    const float* __restrict__ ls, const int* __restrict__ posp,
    __hip_bfloat16* __restrict__ Qp, __hip_bfloat16* __restrict__ Kp,
    __hip_bfloat16* __restrict__ Vt) {
  const int gid = blockIdx.x * blockDim.x + threadIdx.x;  // T*NH, t fastest
  const int t = gid & (TT - 1);
  const int h = gid >> 12;
  const __hip_bfloat16* pr = proj + (size_t)t * NPROJ;
  const float qscale = 0.20412414523193154f * 1.4426950408889634f * __expf(ls[h]);
  const float pos = (float)(t + posp[0]);
  const float invf[8] = {1.0f, 0.31622776601683794f, 0.1f, 0.031622776601683794f,
                         0.01f, 0.0031622776601683794f, 0.001f, 0.00031622776601683794f};
  short8 qv[4], kv[4];
  const short8 z8 = {0, 0, 0, 0, 0, 0, 0, 0};
  qv[3] = z8; kv[3] = z8;
#pragma unroll
  for (int i = 0; i < 8; ++i) {
    qv[0][i] = f2bf(bf2f(pr[h * 8 + i]) * qscale);
    kv[0][i] = f2bf(bf2f(pr[128 + h * 8 + i]));
  }
#pragma unroll
  for (int i = 0; i < 8; ++i) {
    const float ang = pos * invf[i];
    float ss, cc;
    __sincosf(ang, &ss, &cc);
    const float x1q = bf2f(pr[256 + h * 16 + i]), x2q = bf2f(pr[256 + h * 16 + 8 + i]);
    const float x1k = bf2f(pr[512 + h * 16 + i]), x2k = bf2f(pr[512 + h * 16 + 8 + i]);
    qv[1][i] = f2bf((x1q * cc - x2q * ss) * qscale);
    qv[2][i] = f2bf((x1q * ss + x2q * cc) * qscale);
    kv[1][i] = f2bf(x1k * cc - x2k * ss);
    kv[2][i] = f2bf(x1k * ss + x2k * cc);
  }
  short8* qdst = reinterpret_cast<short8*>(Qp + ((size_t)h * TT + t) * 32);
  short8* kdst = reinterpret_cast<short8*>(Kp + ((size_t)h * TT + t) * 32);
#pragma unroll
  for (int p = 0; p < 4; ++p) { qdst[p] = qv[p]; kdst[p] = kv[p]; }
#pragma unroll
  for (int i = 0; i < 32; ++i)
    Vt[((size_t)h * 32 + i) * TT + t] = pr[768 + h * 32 + i];
}

// ---------------- causal flash attention ----------------
// 128 threads = 2 independent waves, 16 q-rows/wave, KV tiles of 64.
// No __syncthreads: each wave uses its private Plds slice.
// Block swizzle: each XCD gets 2 heads so K/V (1 MiB) fits its private L2.
__global__ __launch_bounds__(128) void k_attn(const __hip_bfloat16* __restrict__ Qp,
    const __hip_bfloat16* __restrict__ Kp, const __hip_bfloat16* __restrict__ Vt,
    __hip_bfloat16* __restrict__ Ob) {
  __shared__ alignas(16) __hip_bfloat16 Plds[2][16][72];
  const int lin = blockIdx.x;          // 0..2047
  const int xcd = lin & 7;
  const int idx = lin >> 3;            // 0..255
  const int h = xcd * 2 + (idx >> 7);  // 2 heads per XCD
  const int qb = idx & 127;            // 0..127 (32 q-rows per block)
  const int tid = threadIdx.x;
  const int lane = tid & 63, w = tid >> 6;
  const int q0 = qb * 32 + w * 16;
  const int g = lane >> 4, c = lane & 15;
  const short8 qf = *reinterpret_cast<const short8*>(Qp + ((size_t)h * TT + q0 + c) * 32 + 8 * g);
  f32x4 o0 = {0.f, 0.f, 0.f, 0.f}, o1 = {0.f, 0.f, 0.f, 0.f};
  const f32x4 zz = {0.f, 0.f, 0.f, 0.f};
  float mst[4] = {-1e30f, -1e30f, -1e30f, -1e30f};
  float lsum[4] = {0.f, 0.f, 0.f, 0.f};
  const int ntiles = (qb >> 1) + 1;
  const size_t kbase = (size_t)h * TT * 32;

  short8 kf[4];
#pragma unroll
  for (int ct = 0; ct < 4; ++ct)
    kf[ct] = *reinterpret_cast<const short8*>(Kp + kbase + (size_t)(ct * 16 + c) * 32 + 8 * g);

  for (int it = 0; it < ntiles; ++it) {
    const int kv0 = it * 64;
    // V loads for this tile (early issue — latency hides under QK + softmax)
    const size_t vbase = ((size_t)h * 32 + c) * TT + kv0 + 8 * g;
    const short8 v00 = *reinterpret_cast<const short8*>(Vt + vbase);
    const short8 v01 = *reinterpret_cast<const short8*>(Vt + vbase + 32);
    const short8 v10 = *reinterpret_cast<const short8*>(Vt + vbase + (size_t)16 * TT);
    const short8 v11 = *reinterpret_cast<const short8*>(Vt + vbase + (size_t)16 * TT + 32);
    // K prefetch for next tile
    short8 kn[4];
    if (it + 1 < ntiles) {
#pragma unroll
      for (int ct = 0; ct < 4; ++ct)
        kn[ct] = *reinterpret_cast<const short8*>(Kp + kbase +
                     (size_t)(kv0 + 64 + ct * 16 + c) * 32 + 8 * g);
    }
    f32x4 s[4];
#pragma unroll
    for (int ct = 0; ct < 4; ++ct)
      s[ct] = __builtin_amdgcn_mfma_f32_16x16x32_bf16(qf, kf[ct], zz, 0, 0, 0);
    if (kv0 + 63 > q0) {  // diagonal tiles: causal mask
#pragma unroll
      for (int ct = 0; ct < 4; ++ct)
#pragma unroll
        for (int j = 0; j < 4; ++j)
          if (kv0 + ct * 16 + c > q0 + g * 4 + j) s[ct][j] = -1e30f;
    }
#pragma unroll
    for (int j = 0; j < 4; ++j) {
      float mx = fmaxf(fmaxf(s[0][j], s[1][j]), fmaxf(s[2][j], s[3][j]));
      mx = fmaxf(mx, __shfl_xor(mx, 1, 64));
      mx = fmaxf(mx, __shfl_xor(mx, 2, 64));
      mx = fmaxf(mx, __shfl_xor(mx, 4, 64));
      mx = fmaxf(mx, __shfl_xor(mx, 8, 64));
      const float nm = fmaxf(mst[j], mx);
      float sum = 0.f;
#pragma unroll
      for (int ct = 0; ct < 4; ++ct) {
        const float p = exp2f(s[ct][j] - nm);   // log2(e) pre-folded into Q scale
        s[ct][j] = p;
        sum += p;
      }
      sum += __shfl_xor(sum, 1, 64);
      sum += __shfl_xor(sum, 2, 64);
      sum += __shfl_xor(sum, 4, 64);
      sum += __shfl_xor(sum, 8, 64);
      const float alpha = exp2f(mst[j] - nm);
      lsum[j] = lsum[j] * alpha + sum;
      mst[j] = nm;
      o0[j] *= alpha;
      o1[j] *= alpha;
    }
    // per-wave private LDS transpose of P (no block barrier needed)
#pragma unroll
    for (int ct = 0; ct < 4; ++ct)
#pragma unroll
      for (int j = 0; j < 4; ++j)
        Plds[w][g * 4 + j][ct * 16 + c] = __float2bfloat16(s[ct][j]);
    const short8 pf0 = *reinterpret_cast<const short8*>(&Plds[w][c][8 * g]);
    const short8 pf1 = *reinterpret_cast<const short8*>(&Plds[w][c][32 + 8 * g]);
    o0 = __builtin_amdgcn_mfma_f32_16x16x32_bf16(pf0, v00, o0, 0, 0, 0);
    o0 = __builtin_amdgcn_mfma_f32_16x16x32_bf16(pf1, v01, o0, 0, 0, 0);
    o1 = __builtin_amdgcn_mfma_f32_16x16x32_bf16(pf0, v10, o1, 0, 0, 0);
    o1 = __builtin_amdgcn_mfma_f32_16x16x32_bf16(pf1, v11, o1, 0, 0, 0);
#pragma unroll
    for (int ct = 0; ct < 4; ++ct) kf[ct] = kn[ct];
  }
#pragma unroll
  for (int j = 0; j < 4; ++j) {
    const float inv = 1.0f / lsum[j];
    const int row = q0 + g * 4 + j;
    Ob[(size_t)row * DATTN + h * 32 + c] = __float2bfloat16(o0[j] * inv);
    Ob[(size_t)row * DATTN + h * 32 + 16 + c] = __float2bfloat16(o1[j] * inv);
  }
}

extern "C" void kernel_launch(void* const* d_in, const int* in_sizes, int n_in,
                              void* d_out, int out_size, void* d_ws, size_t ws_size,
                              hipStream_t stream) {
  const float* x   = (const float*)d_in[0];
  const float* qsw = (const float*)d_in[1];
  const float* ksw = (const float*)d_in[2];
  const float* qgw = (const float*)d_in[3];
  const float* kgw = (const float*)d_in[4];
  const float* vw  = (const float*)d_in[5];
  const float* ow  = (const float*)d_in[6];
  const float* ls  = (const float*)d_in[7];
  const int* posp  = (const int*)d_in[9];

  size_t off = 0;
  auto alloc = [&](size_t bytes) {
    char* p = (char*)d_ws + off;
    off += (bytes + 255) & ~(size_t)255;
    return (void*)p;
  };
  __hip_bfloat16* Xbf  = (__hip_bfloat16*)alloc((size_t)TT * DM * 2);
  __hip_bfloat16* Wcat = (__hip_bfloat16*)alloc((size_t)NPROJ * DM * 2);
  __hip_bfloat16* OW   = (__hip_bfloat16*)alloc((size_t)DM * DATTN * 2);
  __hip_bfloat16* proj = (__hip_bfloat16*)alloc((size_t)TT * NPROJ * 2);
  __hip_bfloat16* Qp   = (__hip_bfloat16*)alloc((size_t)NH * TT * 32 * 2);
  __hip_bfloat16* Kpk  = (__hip_bfloat16*)alloc((size_t)NH * TT * 32 * 2);
  __hip_bfloat16* Vt   = (__hip_bfloat16*)alloc((size_t)NH * 32 * TT * 2);
  __hip_bfloat16* Ob   = (__hip_bfloat16*)alloc((size_t)TT * DATTN * 2);

  k_f32_to_bf16<<<dim3((TT * DM / 4) / 256), 256, 0, stream>>>(x, Xbf, TT * DM / 4);
  k_f32_to_bf16<<<dim3((DM * DATTN / 4) / 256), 256, 0, stream>>>(ow, OW, DM * DATTN / 4);
  k_pack_wcat<<<dim3((NPROJ * DM / 4) / 256), 256, 0, stream>>>(qsw, ksw, qgw, kgw, vw, Wcat,
                                                                NPROJ * DM / 4);
  k_gemm_bt<1><<<dim3(TT / 128, NPROJ / 128), 256, 0, stream>>>(Xbf, Wcat, (void*)proj,
                                                                TT, NPROJ, DM);
  k_rope_pack<<<dim3(TT * NH / 256), 256, 0, stream>>>(proj, ls, posp, Qp, Kpk, Vt);
  k_attn<<<dim3(2048), 128, 0, stream>>>(Qp, Kpk, Vt, Ob);
  k_gemm_bt<0><<<dim3(TT / 128, DM / 128), 256, 0, stream>>>(Ob, OW, (void*)d_out,
                                                             TT, DM, DATTN);
}

// Round 3
// 161.427 us; speedup vs baseline: 1.4508x; 1.3186x over previous
//
#include <hip/hip_runtime.h>
#include <hip/hip_bf16.h>

typedef __attribute__((ext_vector_type(8))) short short8;
typedef __attribute__((ext_vector_type(4))) short short4v;
typedef __attribute__((ext_vector_type(4))) float f32x4;

#define TT 4096
#define DM 1024
#define NH 16
#define NPROJ 1280   // 128 qs + 128 ks + 256 qg + 256 kg + 512 v
#define DATTN 512

static __device__ __forceinline__ short f2bf(float f) {
  __hip_bfloat16 h = __float2bfloat16(f);
  return *reinterpret_cast<short*>(&h);
}
static __device__ __forceinline__ float bf2f(__hip_bfloat16 h) { return __bfloat162float(h); }

// ---------------- fp32 -> bf16 convert (x, out_w) ----------------
__global__ __launch_bounds__(256) void k_f32_to_bf16(const float* __restrict__ in,
                                                     __hip_bfloat16* __restrict__ out, int n4) {
  int i = blockIdx.x * blockDim.x + threadIdx.x;
  if (i >= n4) return;
  float4 v = reinterpret_cast<const float4*>(in)[i];
  short4v o;
  o[0] = f2bf(v.x); o[1] = f2bf(v.y); o[2] = f2bf(v.z); o[3] = f2bf(v.w);
  reinterpret_cast<short4v*>(out)[i] = o;
}

// ---------------- concat 5 weight matrices into (1280,1024) bf16 ----------------
__global__ __launch_bounds__(256) void k_pack_wcat(const float* __restrict__ qs,
    const float* __restrict__ ks, const float* __restrict__ qg, const float* __restrict__ kg,
    const float* __restrict__ vw, __hip_bfloat16* __restrict__ w, int n4) {
  int i = blockIdx.x * blockDim.x + threadIdx.x;
  if (i >= n4) return;
  int idx = i * 4;
  int row = idx >> 10;
  int col = idx & 1023;
  const float* src;
  if (row < 128)      src = qs + (size_t)row * DM;
  else if (row < 256) src = ks + (size_t)(row - 128) * DM;
  else if (row < 512) src = qg + (size_t)(row - 256) * DM;
  else if (row < 768) src = kg + (size_t)(row - 512) * DM;
  else                src = vw + (size_t)(row - 768) * DM;
  float4 v = *reinterpret_cast<const float4*>(src + col);
  short4v o;
  o[0] = f2bf(v.x); o[1] = f2bf(v.y); o[2] = f2bf(v.z); o[3] = f2bf(v.w);
  *reinterpret_cast<short4v*>(w + idx) = o;
}

// ---------------- bf16 GEMM, B^T layout: C[m][n] = sum_k A[m][k]*B[n][k] ----------------
template<int OUT_BF16>
__global__ __launch_bounds__(256) void k_gemm_bt(const __hip_bfloat16* __restrict__ A,
    const __hip_bfloat16* __restrict__ B, void* __restrict__ Cv, int M, int N, int K) {
  __shared__ alignas(16) __hip_bfloat16 lA[128 * 32];
  __shared__ alignas(16) __hip_bfloat16 lB[128 * 32];
  const int tid = threadIdx.x;
  const int lane = tid & 63;
  const int wid = tid >> 6;
  const int m0 = blockIdx.x * 128, n0 = blockIdx.y * 128;
  const int wm = (wid >> 1) * 64, wn = (wid & 1) * 64;
  const int srow = tid >> 2;          // 0..63
  const int scol = (tid & 3) * 8;     // bf16 elements
  const int fr = lane & 15, fk = (lane >> 4) * 8;
  f32x4 acc[4][4];
  const f32x4 zz = {0.f, 0.f, 0.f, 0.f};
#pragma unroll
  for (int m = 0; m < 4; ++m)
#pragma unroll
    for (int n = 0; n < 4; ++n) acc[m][n] = zz;

  for (int kt = 0; kt < K; kt += 32) {
    __syncthreads();
    {
      const __hip_bfloat16* ga0 = A + (size_t)(m0 + srow) * K + kt + scol;
      const __hip_bfloat16* ga1 = A + (size_t)(m0 + 64 + srow) * K + kt + scol;
      const __hip_bfloat16* gb0 = B + (size_t)(n0 + srow) * K + kt + scol;
      const __hip_bfloat16* gb1 = B + (size_t)(n0 + 64 + srow) * K + kt + scol;
      __builtin_amdgcn_global_load_lds((const __attribute__((address_space(1))) void*)ga0,
          (__attribute__((address_space(3))) void*)(lA + srow * 32 + scol), 16, 0, 0);
      __builtin_amdgcn_global_load_lds((const __attribute__((address_space(1))) void*)ga1,
          (__attribute__((address_space(3))) void*)(lA + (64 + srow) * 32 + scol), 16, 0, 0);
      __builtin_amdgcn_global_load_lds((const __attribute__((address_space(1))) void*)gb0,
          (__attribute__((address_space(3))) void*)(lB + srow * 32 + scol), 16, 0, 0);
      __builtin_amdgcn_global_load_lds((const __attribute__((address_space(1))) void*)gb1,
          (__attribute__((address_space(3))) void*)(lB + (64 + srow) * 32 + scol), 16, 0, 0);
    }
    __syncthreads();
    short8 af[4], bfr[4];
#pragma unroll
    for (int m = 0; m < 4; ++m)
      af[m] = *reinterpret_cast<const short8*>(lA + (wm + m * 16 + fr) * 32 + fk);
#pragma unroll
    for (int n = 0; n < 4; ++n)
      bfr[n] = *reinterpret_cast<const short8*>(lB + (wn + n * 16 + fr) * 32 + fk);
#pragma unroll
    for (int m = 0; m < 4; ++m)
#pragma unroll
      for (int n = 0; n < 4; ++n)
        acc[m][n] = __builtin_amdgcn_mfma_f32_16x16x32_bf16(af[m], bfr[n], acc[m][n], 0, 0, 0);
  }
  const int cr = (lane >> 4) * 4, cc = lane & 15;
#pragma unroll
  for (int m = 0; m < 4; ++m)
#pragma unroll
    for (int n = 0; n < 4; ++n)
#pragma unroll
      for (int j = 0; j < 4; ++j) {
        const int row = m0 + wm + m * 16 + cr + j;
        const int col = n0 + wn + n * 16 + cc;
        if (OUT_BF16)
          ((__hip_bfloat16*)Cv)[(size_t)row * N + col] = __float2bfloat16(acc[m][n][j]);
        else
          ((float*)Cv)[(size_t)row * N + col] = acc[m][n][j];
      }
}

// ---------------- RoPE + pack Q/K (H,T,32) and V^T (H,32,T) ----------------
// qscale folds 1/sqrt(24) * exp(logit_scale) * log2(e)  (softmax uses exp2)
__global__ __launch_bounds__(256) void k_rope_pack(const __hip_bfloat16* __restrict__ proj,
    const float* __restrict__ ls, const int* __restrict__ posp,
    __hip_bfloat16* __restrict__ Qp, __hip_bfloat16* __restrict__ Kp,
    __hip_bfloat16* __restrict__ Vt) {
  const int gid = blockIdx.x * blockDim.x + threadIdx.x;  // T*NH, t fastest
  const int t = gid & (TT - 1);
  const int h = gid >> 12;
  const __hip_bfloat16* pr = proj + (size_t)t * NPROJ;
  const float qscale = 0.20412414523193154f * 1.4426950408889634f * __expf(ls[h]);
  const float pos = (float)(t + posp[0]);
  const float invf[8] = {1.0f, 0.31622776601683794f, 0.1f, 0.031622776601683794f,
                         0.01f, 0.0031622776601683794f, 0.001f, 0.00031622776601683794f};
  short8 qv[4], kv[4];
  const short8 z8 = {0, 0, 0, 0, 0, 0, 0, 0};
  qv[3] = z8; kv[3] = z8;
#pragma unroll
  for (int i = 0; i < 8; ++i) {
    qv[0][i] = f2bf(bf2f(pr[h * 8 + i]) * qscale);
    kv[0][i] = f2bf(bf2f(pr[128 + h * 8 + i]));
  }
#pragma unroll
  for (int i = 0; i < 8; ++i) {
    const float ang = pos * invf[i];
    float ss, cc;
    __sincosf(ang, &ss, &cc);
    const float x1q = bf2f(pr[256 + h * 16 + i]), x2q = bf2f(pr[256 + h * 16 + 8 + i]);
    const float x1k = bf2f(pr[512 + h * 16 + i]), x2k = bf2f(pr[512 + h * 16 + 8 + i]);
    qv[1][i] = f2bf((x1q * cc - x2q * ss) * qscale);
    qv[2][i] = f2bf((x1q * ss + x2q * cc) * qscale);
    kv[1][i] = f2bf(x1k * cc - x2k * ss);
    kv[2][i] = f2bf(x1k * ss + x2k * cc);
  }
  short8* qdst = reinterpret_cast<short8*>(Qp + ((size_t)h * TT + t) * 32);
  short8* kdst = reinterpret_cast<short8*>(Kp + ((size_t)h * TT + t) * 32);
#pragma unroll
  for (int p = 0; p < 4; ++p) { qdst[p] = qv[p]; kdst[p] = kv[p]; }
#pragma unroll
  for (int i = 0; i < 32; ++i)
    Vt[((size_t)h * 32 + i) * TT + t] = pr[768 + h * 32 + i];
}

// ---------------- causal flash attention, swapped-QK layout ----------------
// 128 threads = 2 independent waves; wave w handles 16-row q-tile r (w0: sub,
// w1: 255-sub) so every block does ~65 KV tiles -> perfect balance.
// mfma(K,Q): lane owns ONE q-row (q = q0 + (lane&15)), k = ct*16+g*4+j.
// Softmax: in-register tree + 2 shfl_xor; alpha redistributed via 4 bpermutes.
__global__ __launch_bounds__(128) void k_attn(const __hip_bfloat16* __restrict__ Qp,
    const __hip_bfloat16* __restrict__ Kp, const __hip_bfloat16* __restrict__ Vt,
    __hip_bfloat16* __restrict__ Ob) {
  __shared__ alignas(16) __hip_bfloat16 Plds[2][16][72];
  const int lin = blockIdx.x;          // 0..2047
  const int xcd = lin & 7;
  const int idx = lin >> 3;            // 0..255
  const int h = xcd * 2 + (idx >> 7);  // 2 heads per XCD (K/V fits 4MiB L2)
  const int sub = idx & 127;
  const int tid = threadIdx.x;
  const int lane = tid & 63, w = tid >> 6;
  const int r = w ? (255 - sub) : sub; // 16-row tile index 0..255
  const int q0 = r * 16;
  const int g = lane >> 4, c = lane & 15;
  const short8 qf = *reinterpret_cast<const short8*>(Qp + ((size_t)h * TT + q0 + c) * 32 + 8 * g);
  f32x4 o0 = {0.f, 0.f, 0.f, 0.f}, o1 = {0.f, 0.f, 0.f, 0.f};
  const f32x4 zz = {0.f, 0.f, 0.f, 0.f};
  float mst = -1e30f, lsum = 0.f;
  const int ntiles = (r >> 2) + 1;
  const size_t kbase = (size_t)h * TT * 32;

  short8 kf[4];
#pragma unroll
  for (int ct = 0; ct < 4; ++ct)
    kf[ct] = *reinterpret_cast<const short8*>(Kp + kbase + (size_t)(ct * 16 + c) * 32 + 8 * g);

  for (int it = 0; it < ntiles; ++it) {
    const int kv0 = it * 64;
    // V loads for this tile (early issue)
    const size_t vbase = ((size_t)h * 32 + c) * TT + kv0 + 8 * g;
    const short8 v00 = *reinterpret_cast<const short8*>(Vt + vbase);
    const short8 v01 = *reinterpret_cast<const short8*>(Vt + vbase + 32);
    const short8 v10 = *reinterpret_cast<const short8*>(Vt + vbase + (size_t)16 * TT);
    const short8 v11 = *reinterpret_cast<const short8*>(Vt + vbase + (size_t)16 * TT + 32);
    // K prefetch for next tile
    short8 kn[4];
    if (it + 1 < ntiles) {
#pragma unroll
      for (int ct = 0; ct < 4; ++ct)
        kn[ct] = *reinterpret_cast<const short8*>(Kp + kbase +
                     (size_t)(kv0 + 64 + ct * 16 + c) * 32 + 8 * g);
    }
    f32x4 s[4];
#pragma unroll
    for (int ct = 0; ct < 4; ++ct)
      s[ct] = __builtin_amdgcn_mfma_f32_16x16x32_bf16(kf[ct], qf, zz, 0, 0, 0);  // swapped
    if (it == ntiles - 1) {  // diagonal tile: causal mask (k > q)
#pragma unroll
      for (int ct = 0; ct < 4; ++ct)
#pragma unroll
        for (int j = 0; j < 4; ++j)
          if (kv0 + ct * 16 + g * 4 + j > q0 + c) s[ct][j] = -1e30f;
    }
    // lane-local row max over 16 values + 2 shuffles across g-groups
    float pm = s[0][0];
#pragma unroll
    for (int ct = 0; ct < 4; ++ct)
#pragma unroll
      for (int j = 0; j < 4; ++j) pm = fmaxf(pm, s[ct][j]);
    pm = fmaxf(pm, __shfl_xor(pm, 16, 64));
    pm = fmaxf(pm, __shfl_xor(pm, 32, 64));
    const float nm = fmaxf(mst, pm);
    float psum[4];
#pragma unroll
    for (int ct = 0; ct < 4; ++ct) {
#pragma unroll
      for (int j = 0; j < 4; ++j) s[ct][j] = exp2f(s[ct][j] - nm);
      psum[ct] = (s[ct][0] + s[ct][1]) + (s[ct][2] + s[ct][3]);
    }
    float sum = (psum[0] + psum[1]) + (psum[2] + psum[3]);
    sum += __shfl_xor(sum, 16, 64);
    sum += __shfl_xor(sum, 32, 64);
    const float alpha = exp2f(mst - nm);
    lsum = lsum * alpha + sum;
    mst = nm;
    // redistribute alpha to O-row owners (rows g*4+j live at lane g*4+j)
    float aj[4];
#pragma unroll
    for (int j = 0; j < 4; ++j) aj[j] = __shfl(alpha, g * 4 + j, 64);
#pragma unroll
    for (int j = 0; j < 4; ++j) { o0[j] *= aj[j]; o1[j] *= aj[j]; }
    // P -> LDS (packed pairs), per-wave private slice, no barrier
#pragma unroll
    for (int ct = 0; ct < 4; ++ct)
#pragma unroll
      for (int jp = 0; jp < 2; ++jp) {
        const unsigned lo = (unsigned short)f2bf(s[ct][2 * jp]);
        const unsigned hi = (unsigned short)f2bf(s[ct][2 * jp + 1]);
        *reinterpret_cast<unsigned*>(&Plds[w][c][ct * 16 + g * 4 + 2 * jp]) = lo | (hi << 16);
      }
    const short8 pf0 = *reinterpret_cast<const short8*>(&Plds[w][c][8 * g]);
    const short8 pf1 = *reinterpret_cast<const short8*>(&Plds[w][c][32 + 8 * g]);
    o0 = __builtin_amdgcn_mfma_f32_16x16x32_bf16(pf0, v00, o0, 0, 0, 0);
    o0 = __builtin_amdgcn_mfma_f32_16x16x32_bf16(pf1, v01, o0, 0, 0, 0);
    o1 = __builtin_amdgcn_mfma_f32_16x16x32_bf16(pf0, v10, o1, 0, 0, 0);
    o1 = __builtin_amdgcn_mfma_f32_16x16x32_bf16(pf1, v11, o1, 0, 0, 0);
#pragma unroll
    for (int ct = 0; ct < 4; ++ct) kf[ct] = kn[ct];
  }
#pragma unroll
  for (int j = 0; j < 4; ++j) {
    const float inv = 1.0f / __shfl(lsum, g * 4 + j, 64);
    const int row = q0 + g * 4 + j;
    Ob[(size_t)row * DATTN + h * 32 + c] = __float2bfloat16(o0[j] * inv);
    Ob[(size_t)row * DATTN + h * 32 + 16 + c] = __float2bfloat16(o1[j] * inv);
  }
}

extern "C" void kernel_launch(void* const* d_in, const int* in_sizes, int n_in,
                              void* d_out, int out_size, void* d_ws, size_t ws_size,
                              hipStream_t stream) {
  const float* x   = (const float*)d_in[0];
  const float* qsw = (const float*)d_in[1];
  const float* ksw = (const float*)d_in[2];
  const float* qgw = (const float*)d_in[3];
  const float* kgw = (const float*)d_in[4];
  const float* vw  = (const float*)d_in[5];
  const float* ow  = (const float*)d_in[6];
  const float* ls  = (const float*)d_in[7];
  const int* posp  = (const int*)d_in[9];

  size_t off = 0;
  auto alloc = [&](size_t bytes) {
    char* p = (char*)d_ws + off;
    off += (bytes + 255) & ~(size_t)255;
    return (void*)p;
  };
  __hip_bfloat16* Xbf  = (__hip_bfloat16*)alloc((size_t)TT * DM * 2);
  __hip_bfloat16* Wcat = (__hip_bfloat16*)alloc((size_t)NPROJ * DM * 2);
  __hip_bfloat16* OW   = (__hip_bfloat16*)alloc((size_t)DM * DATTN * 2);
  __hip_bfloat16* proj = (__hip_bfloat16*)alloc((size_t)TT * NPROJ * 2);
  __hip_bfloat16* Qp   = (__hip_bfloat16*)alloc((size_t)NH * TT * 32 * 2);
  __hip_bfloat16* Kpk  = (__hip_bfloat16*)alloc((size_t)NH * TT * 32 * 2);
  __hip_bfloat16* Vt   = (__hip_bfloat16*)alloc((size_t)NH * 32 * TT * 2);
  __hip_bfloat16* Ob   = (__hip_bfloat16*)alloc((size_t)TT * DATTN * 2);

  k_f32_to_bf16<<<dim3((TT * DM / 4) / 256), 256, 0, stream>>>(x, Xbf, TT * DM / 4);
  k_f32_to_bf16<<<dim3((DM * DATTN / 4) / 256), 256, 0, stream>>>(ow, OW, DM * DATTN / 4);
  k_pack_wcat<<<dim3((NPROJ * DM / 4) / 256), 256, 0, stream>>>(qsw, ksw, qgw, kgw, vw, Wcat,
                                                                NPROJ * DM / 4);
  k_gemm_bt<1><<<dim3(TT / 128, NPROJ / 128), 256, 0, stream>>>(Xbf, Wcat, (void*)proj,
                                                                TT, NPROJ, DM);
  k_rope_pack<<<dim3(TT * NH / 256), 256, 0, stream>>>(proj, ls, posp, Qp, Kpk, Vt);
  k_attn<<<dim3(2048), 128, 0, stream>>>(Qp, Kpk, Vt, Ob);
  k_gemm_bt<0><<<dim3(TT / 128, DM / 128), 256, 0, stream>>>(Ob, OW, (void*)d_out,
                                                             TT, DM, DATTN);
}